// Round 2
// baseline (538.373 us; speedup 1.0000x reference)
//
#include <hip/hip_runtime.h>

// HaloAttn on MI355X (gfx950). Inputs/outputs are FLOAT32 (per reference dtypes);
// internal compute in bf16 MFMA (validation tolerance is 2% of max|ref|).
// kernel 0: PK = k_pos@Wk [208][256] f32, PQ = q_pos@Wq [64][256] f32 into d_ws.
// kernel 1: fully fused per-window attention (1024 WGs): K/V/Q proj (MFMA, acc-init from
//           PK/PQ), QK^T + masked softmax in registers, PV, per-head partial out-proj.

using bf16x8 = __attribute__((ext_vector_type(8))) short;  // 8 bf16 = 4 VGPRs (MFMA A/B frag)
using f32x4  = __attribute__((ext_vector_type(4))) float;  // MFMA C/D frag

__device__ __forceinline__ unsigned short f2bf(float f) {
  unsigned int x = __float_as_uint(f);
  x += 0x7fffu + ((x >> 16) & 1u);  // round-nearest-even
  return (unsigned short)(x >> 16);
}
__device__ __forceinline__ unsigned int pack2(float a, float b) {
  return (unsigned int)f2bf(a) | ((unsigned int)f2bf(b) << 16);
}
// p/14 for 0 <= p < 208
__device__ __forceinline__ int div14(int p) { return (p * 4682) >> 16; }

// 8 strided f32 loads -> bf16 frag: W[k0+j][col], row stride 256
__device__ __forceinline__ bf16x8 loadW8(const float* __restrict__ w) {
  bf16x8 v;
#pragma unroll
  for (int j = 0; j < 8; ++j) v[j] = (short)f2bf(w[j * 256]);
  return v;
}

// ---------------- kernel 0: positional-embedding projections (f32) ----------------
__global__ __launch_bounds__(256) void pos_proj_kernel(
    const float* __restrict__ Wq, const float* __restrict__ Wk,
    float* __restrict__ PK, float* __restrict__ PQ) {
  __shared__ float pr[256];
  const int row = blockIdx.x, o = threadIdx.x;
  const float* Wm;
  float* dst;
  int ii, jj;
  if (row < 208) {                      // PK rows (kv positions), 196..207 are pad -> 0
    if (row >= 196) { PK[row * 256 + o] = 0.f; return; }
    ii = row / 14; jj = row % 14;
    Wm = Wk; dst = PK + row * 256;
  } else {                              // PQ rows (query positions, center of window)
    int qp = row - 208;
    ii = (qp >> 3) + 3; jj = (qp & 7) + 3;
    Wm = Wq; dst = PQ + qp * 256;
  }
  const int cl = o & 127, mfreq = cl >> 1;
  float t = powf(10000.f, (float)mfreq * (1.f / 64.f));
  float base = (o < 128) ? (float)(ii + 1) : (float)(jj + 1);
  float arg = base * (6.283185307179586f / 14.000001f) / t;  // (idx+1)/(14+1e-6)*2pi / dim_t
  pr[o] = (cl & 1) ? cosf(arg) : sinf(arg);
  __syncthreads();
  float acc = 0.f;
  for (int c = 0; c < 256; ++c) acc = fmaf(pr[c], Wm[c * 256 + o], acc);
  dst[o] = acc;
}

// ---------------- kernel 1: fused halo attention ----------------
// LDS: strides padded so 16-lane frag reads are <=2-way bank aliased (free per m136),
// all 16B reads 16B-aligned. Total 64768 B -> 2 WGs/CU.
struct alignas(16) SM {
  unsigned short sX[208 * 40];   // raw x window (bf16), one 32-ch chunk
  unsigned short sK[224 * 40];   // K_h [kv][32]  (rows 208..223 stay zero)
  unsigned short sVt[32 * 232];  // V_h^T [32][kv] (cols 208..231 stay zero)
  unsigned short sQ[64 * 40];    // Q_h [qm][32]
  unsigned short sP[64 * 40];    // softmax chunk [qm][32]
  unsigned short sO[64 * 40];    // O_h [qm][32]
};

__global__ __launch_bounds__(256, 2) void halo_attn_kernel(
    const float* __restrict__ xg,
    const float* __restrict__ Wq,
    const float* __restrict__ Wk,
    const float* __restrict__ Wv,
    const float* __restrict__ Wp,
    const float* __restrict__ bp,
    const float* __restrict__ PK,
    const float* __restrict__ PQ,
    float* __restrict__ out) {
  __shared__ SM sm;
  const int wid = blockIdx.x;
  const int b = wid >> 8, widx = wid & 255;
  const int wy = widx >> 4, wx = widx & 15;
  const int tid = threadIdx.x;
  const int wave = tid >> 6, lane = tid & 63, q = lane >> 4, r = lane & 15;
  constexpr float SCALE = 0.17677669529663687f;  // 32^-0.5

  // zero the pad rows/cols once (never rewritten afterwards)
  for (int idx = tid; idx < 640; idx += 256) sm.sK[208 * 40 + idx] = 0;
  for (int idx = tid; idx < 1024; idx += 256) {
    int rr = idx >> 5, c2 = idx & 31;
    if (c2 < 24) sm.sVt[rr * 232 + 208 + c2] = 0;
  }

  f32x4 oacc[16];  // this wave's 16 output rows x 256 cols (16 N-tiles)
#pragma unroll
  for (int nt = 0; nt < 16; ++nt) oacc[nt] = (f32x4){0.f, 0.f, 0.f, 0.f};

  // P1 wave roles: waves 0/1 -> K (dh halves 0/1) + Q tiles 0..1; waves 2/3 -> V + Q tiles 2..3
  const int ntA = wave & 1;
  const int qbase = (wave >> 1) * 2;
  const bool mainIsK = (wave < 2);
  const float* Wmain = mainIsK ? Wk : Wv;

  for (int h = 0; h < 8; ++h) {
    const int colMain = h * 32 + ntA * 16 + r;
    // ---- P1: K/V/Q projections (K acc-init = PK, Q acc-init = PQ, V = 0) ----
    f32x4 acc[13];
#pragma unroll
    for (int mt = 0; mt < 13; ++mt) {
      if (mainIsK) {
#pragma unroll
        for (int g = 0; g < 4; ++g)
          acc[mt][g] = PK[(mt * 16 + q * 4 + g) * 256 + colMain];
      } else {
        acc[mt] = (f32x4){0.f, 0.f, 0.f, 0.f};
      }
    }
    f32x4 qacc[2];
#pragma unroll
    for (int tq = 0; tq < 2; ++tq)
#pragma unroll
      for (int g = 0; g < 4; ++g)
        qacc[tq][g] = PQ[((qbase + tq) * 16 + q * 4 + g) * 256 + colMain];

    bf16x8 bm = loadW8(Wmain + (q * 8) * 256 + colMain);
    bf16x8 bq = loadW8(Wq + (q * 8) * 256 + colMain);
    for (int cc = 0; cc < 8; ++cc) {
      __syncthreads();  // previous chunk's frag reads done before restage
      // stage raw x window chunk [208 rows][32 ch], f32 -> bf16, as 16B LDS segments
      for (int tsk = tid; tsk < 832; tsk += 256) {
        int p = tsk >> 2, seg = tsk & 3;
        int i = div14(p), j = p - i * 14;
        int y = wy * 8 - 3 + i, x = wx * 8 - 3 + j;
        uint4 w = {0u, 0u, 0u, 0u};
        if (p < 196 && (unsigned)y < 128u && (unsigned)x < 128u) {
          const float* src = xg + (((b * 128 + y) * 128 + x) << 8) + cc * 32 + seg * 8;
          float4 f0 = *(const float4*)(src);
          float4 f1 = *(const float4*)(src + 4);
          w.x = pack2(f0.x, f0.y); w.y = pack2(f0.z, f0.w);
          w.z = pack2(f1.x, f1.y); w.w = pack2(f1.z, f1.w);
        }
        *(uint4*)&sm.sX[p * 40 + seg * 8] = w;
      }
      bf16x8 bmn = bm, bqn = bq;  // prefetch next chunk's B-frags (overlaps MFMAs)
      if (cc < 7) {
        bmn = loadW8(Wmain + ((cc + 1) * 32 + q * 8) * 256 + colMain);
        bqn = loadW8(Wq + ((cc + 1) * 32 + q * 8) * 256 + colMain);
      }
      __syncthreads();
#pragma unroll
      for (int mt = 0; mt < 13; ++mt) {
        bf16x8 a = *(const bf16x8*)&sm.sX[(mt * 16 + r) * 40 + q * 8];
        acc[mt] = __builtin_amdgcn_mfma_f32_16x16x32_bf16(a, bm, acc[mt], 0, 0, 0);
      }
#pragma unroll
      for (int tq = 0; tq < 2; ++tq) {
        int qm = (qbase + tq) * 16 + r;                   // query row
        int p = ((qm >> 3) + 3) * 14 + (qm & 7) + 3;      // its kv-window position
        bf16x8 a = *(const bf16x8*)&sm.sX[p * 40 + q * 8];
        qacc[tq] = __builtin_amdgcn_mfma_f32_16x16x32_bf16(a, bq, qacc[tq], 0, 0, 0);
      }
      bm = bmn; bq = bqn;
    }
    // write K/V^T/Q to LDS (D-layout: row = q*4+g, col = r)
    if (mainIsK) {
#pragma unroll
      for (int mt = 0; mt < 13; ++mt)
#pragma unroll
        for (int g = 0; g < 4; ++g)
          sm.sK[(mt * 16 + q * 4 + g) * 40 + ntA * 16 + r] = f2bf(acc[mt][g]);
    } else {
#pragma unroll
      for (int mt = 0; mt < 13; ++mt) {
        short4 v4;
        v4.x = (short)f2bf(acc[mt][0]); v4.y = (short)f2bf(acc[mt][1]);
        v4.z = (short)f2bf(acc[mt][2]); v4.w = (short)f2bf(acc[mt][3]);
        *(short4*)&sm.sVt[(ntA * 16 + r) * 232 + mt * 16 + q * 4] = v4;
      }
    }
#pragma unroll
    for (int tq = 0; tq < 2; ++tq)
#pragma unroll
      for (int g = 0; g < 4; ++g)
        sm.sQ[((qbase + tq) * 16 + q * 4 + g) * 40 + ntA * 16 + r] = f2bf(qacc[tq][g]);
    __syncthreads();

    // ---- P2: S = Q K^T (wave owns query rows [16*wave, 16*wave+16)) ----
    bf16x8 aq = *(const bf16x8*)&sm.sQ[(wave * 16 + r) * 40 + q * 8];
    f32x4 s[14];
#pragma unroll
    for (int nt = 0; nt < 14; ++nt) {
      bf16x8 bk = *(const bf16x8*)&sm.sK[(nt * 16 + r) * 40 + q * 8];
      f32x4 z = {0.f, 0.f, 0.f, 0.f};
      s[nt] = __builtin_amdgcn_mfma_f32_16x16x32_bf16(aq, bk, z, 0, 0, 0);
    }
    // scale + halo-validity mask (column n depends on lane only)
#pragma unroll
    for (int nt = 0; nt < 14; ++nt) {
      int n = nt * 16 + r;
      int i = div14(n), j = n - i * 14;
      int y = wy * 8 - 3 + i, x = wx * 8 - 3 + j;
      bool valid = (n < 196) && ((unsigned)y < 128u) && ((unsigned)x < 128u);
#pragma unroll
      for (int g = 0; g < 4; ++g) s[nt][g] = valid ? s[nt][g] * SCALE : -1e30f;
    }
    // softmax per row: reduce over 14 tiles locally, then across the 16-lane group
    float mx[4] = {-1e30f, -1e30f, -1e30f, -1e30f};
#pragma unroll
    for (int nt = 0; nt < 14; ++nt)
#pragma unroll
      for (int g = 0; g < 4; ++g) mx[g] = fmaxf(mx[g], s[nt][g]);
#pragma unroll
    for (int d = 1; d < 16; d <<= 1)
#pragma unroll
      for (int g = 0; g < 4; ++g) mx[g] = fmaxf(mx[g], __shfl_xor(mx[g], d));
    float sum[4] = {0.f, 0.f, 0.f, 0.f};
#pragma unroll
    for (int nt = 0; nt < 14; ++nt)
#pragma unroll
      for (int g = 0; g < 4; ++g) {
        float e = __expf(s[nt][g] - mx[g]);
        s[nt][g] = e; sum[g] += e;
      }
#pragma unroll
    for (int d = 1; d < 16; d <<= 1)
#pragma unroll
      for (int g = 0; g < 4; ++g) sum[g] += __shfl_xor(sum[g], d);
    float inv[4];
#pragma unroll
    for (int g = 0; g < 4; ++g) inv[g] = 1.f / sum[g];
#pragma unroll
    for (int nt = 0; nt < 14; ++nt)
#pragma unroll
      for (int g = 0; g < 4; ++g) s[nt][g] *= inv[g];

    // ---- P3: O = P @ V, chunked over kv (P transits LDS: D-layout -> A-layout) ----
    f32x4 ov[2];
    ov[0] = (f32x4){0.f, 0.f, 0.f, 0.f}; ov[1] = ov[0];
#pragma unroll
    for (int ck = 0; ck < 7; ++ck) {
      __syncthreads();
#pragma unroll
      for (int tq = 0; tq < 2; ++tq)
#pragma unroll
        for (int g = 0; g < 4; ++g)
          sm.sP[(wave * 16 + q * 4 + g) * 40 + tq * 16 + r] = f2bf(s[ck * 2 + tq][g]);
      __syncthreads();
      bf16x8 ap = *(const bf16x8*)&sm.sP[(wave * 16 + r) * 40 + q * 8];
#pragma unroll
      for (int t2 = 0; t2 < 2; ++t2) {
        bf16x8 bv = *(const bf16x8*)&sm.sVt[(t2 * 16 + r) * 232 + ck * 32 + q * 8];
        ov[t2] = __builtin_amdgcn_mfma_f32_16x16x32_bf16(ap, bv, ov[t2], 0, 0, 0);
      }
    }
#pragma unroll
    for (int t2 = 0; t2 < 2; ++t2)
#pragma unroll
      for (int g = 0; g < 4; ++g)
        sm.sO[(wave * 16 + q * 4 + g) * 40 + t2 * 16 + r] = f2bf(ov[t2][g]);
    __syncthreads();

    // ---- P4: partial out-projection: oacc += O_h @ Wproj[h*32:(h+1)*32, :] ----
    bf16x8 ao = *(const bf16x8*)&sm.sO[(wave * 16 + r) * 40 + q * 8];
#pragma unroll
    for (int nt = 0; nt < 16; ++nt) {
      bf16x8 bw = loadW8(Wp + (h * 32 + q * 8) * 256 + nt * 16 + r);
      oacc[nt] = __builtin_amdgcn_mfma_f32_16x16x32_bf16(ao, bw, oacc[nt], 0, 0, 0);
    }
  }

  // ---- epilogue: bias + scatter to [B,H,W,C] (f32) ----
#pragma unroll
  for (int nt = 0; nt < 16; ++nt) {
    int col = nt * 16 + r;
    float bias = bp[col];
#pragma unroll
    for (int g = 0; g < 4; ++g) {
      int m = wave * 16 + q * 4 + g;
      int y = wy * 8 + (m >> 3), x = wx * 8 + (m & 7);
      out[(((b * 128 + y) * 128 + x) << 8) + col] = oacc[nt][g] + bias;
    }
  }
}

extern "C" void kernel_launch(void* const* d_in, const int* in_sizes, int n_in,
                              void* d_out, int out_size, void* d_ws, size_t ws_size,
                              hipStream_t stream) {
  (void)in_sizes; (void)n_in; (void)out_size; (void)ws_size;
  const float* xg = (const float*)d_in[0];
  const float* Wq = (const float*)d_in[1];
  const float* Wk = (const float*)d_in[2];
  const float* Wv = (const float*)d_in[3];
  const float* Wp = (const float*)d_in[4];
  const float* bp = (const float*)d_in[5];
  float* out = (float*)d_out;
  float* PK = (float*)d_ws;       // [208][256] f32
  float* PQ = PK + 208 * 256;     // [64][256] f32

  pos_proj_kernel<<<dim3(272), dim3(256), 0, stream>>>(Wq, Wk, PK, PQ);
  halo_attn_kernel<<<dim3(1024), dim3(256), 0, stream>>>(xg, Wq, Wk, Wv, Wp, bp, PK, PQ, out);
}

// Round 3
// 402.846 us; speedup vs baseline: 1.3364x; 1.3364x over previous
//
#include <hip/hip_runtime.h>

// HaloAttn on MI355X (gfx950). f32 in/out, bf16 MFMA internals.
// FAST PATH (needs ws >= ~101.5 MB):
//   pos_proj:  PK = k_pos@Wk [208][256] f32, PQ = q_pos@Wq [64][256] f32
//   wtrans:    Wt4[mat][n][k] bf16 = transpose of {Wq,Wk,Wv,Wp} (B-frag friendly)
//   qkv_gemm:  XQ/XK/XV [65536][256] bf16 = x @ {Wq,Wk,Wv}  (projection done ONCE)
//   halo_fast: per-window attention staging only 32-ch/head bf16 slices; 2 barriers/head
// FALLBACK: round-2 fused kernel (known-good) if ws_size is too small.

using bf16x8 = __attribute__((ext_vector_type(8))) short;
using f32x4  = __attribute__((ext_vector_type(4))) float;

__device__ __forceinline__ float bf2f(unsigned short u) {
  return __uint_as_float(((unsigned int)u) << 16);
}
__device__ __forceinline__ unsigned short f2bf(float f) {
  unsigned int x = __float_as_uint(f);
  x += 0x7fffu + ((x >> 16) & 1u);
  return (unsigned short)(x >> 16);
}
__device__ __forceinline__ unsigned int pack2(float a, float b) {
  return (unsigned int)f2bf(a) | ((unsigned int)f2bf(b) << 16);
}
__device__ __forceinline__ int div14(int p) { return (p * 4682) >> 16; }

__device__ __forceinline__ bf16x8 loadW8(const float* __restrict__ w) {
  bf16x8 v;
#pragma unroll
  for (int j = 0; j < 8; ++j) v[j] = (short)f2bf(w[j * 256]);
  return v;
}

// ---------------- pos_proj: positional-embedding projections (f32) ----------------
__global__ __launch_bounds__(256) void pos_proj_kernel(
    const float* __restrict__ Wq, const float* __restrict__ Wk,
    float* __restrict__ PK, float* __restrict__ PQ) {
  __shared__ float pr[256];
  const int row = blockIdx.x, o = threadIdx.x;
  const float* Wm;
  float* dst;
  int ii, jj;
  if (row < 208) {
    if (row >= 196) { PK[row * 256 + o] = 0.f; return; }
    ii = row / 14; jj = row % 14;
    Wm = Wk; dst = PK + row * 256;
  } else {
    int qp = row - 208;
    ii = (qp >> 3) + 3; jj = (qp & 7) + 3;
    Wm = Wq; dst = PQ + qp * 256;
  }
  const int cl = o & 127, mfreq = cl >> 1;
  float t = powf(10000.f, (float)mfreq * (1.f / 64.f));
  float base = (o < 128) ? (float)(ii + 1) : (float)(jj + 1);
  float arg = base * (6.283185307179586f / 14.000001f) / t;
  pr[o] = (cl & 1) ? cosf(arg) : sinf(arg);
  __syncthreads();
  float acc = 0.f;
  for (int c = 0; c < 256; ++c) acc = fmaf(pr[c], Wm[c * 256 + o], acc);
  dst[o] = acc;
}

// ---------------- wtrans: Wt4[mat][n][k] = bf16(W[k][n]) ----------------
__global__ __launch_bounds__(256) void wtrans_kernel(
    const float* __restrict__ Wq, const float* __restrict__ Wk,
    const float* __restrict__ Wv, const float* __restrict__ Wp,
    unsigned short* __restrict__ Wt4) {
  const int mat = blockIdx.x >> 8, n = blockIdx.x & 255, k = threadIdx.x;
  const float* src = (mat == 0) ? Wq : (mat == 1) ? Wk : (mat == 2) ? Wv : Wp;
  Wt4[((mat * 256 + n) << 8) + k] = f2bf(src[k * 256 + n]);
}

// ---------------- qkv_gemm: X{Q,K,V} = x @ W, bf16 out ----------------
// grid (512, 3): blockIdx.x = 128-row M-tile, blockIdx.y = matrix.
__global__ __launch_bounds__(256, 2) void qkv_gemm_kernel(
    const float* __restrict__ xg, const unsigned short* __restrict__ Wt4,
    unsigned short* __restrict__ outbase) {
  __shared__ unsigned short sA[128 * 72];  // bf16 A-tile, pad 72 (2-way free)
  const int m0 = blockIdx.x << 7, mat = blockIdx.y;
  const unsigned short* Wt = Wt4 + (mat << 16);
  unsigned short* out = outbase + mat * 16777216;
  const int tid = threadIdx.x;
  const int wave = tid >> 6, lane = tid & 63, q = lane >> 4, r = lane & 15;

  f32x4 acc[2][16];
#pragma unroll
  for (int mt = 0; mt < 2; ++mt)
#pragma unroll
    for (int nt = 0; nt < 16; ++nt) acc[mt][nt] = (f32x4){0.f, 0.f, 0.f, 0.f};

  for (int cc = 0; cc < 4; ++cc) {
    __syncthreads();
    // stage x[m0..m0+127][cc*64..+63] f32 -> bf16 LDS
    for (int t = tid; t < 1024; t += 256) {
      int row = t >> 3, seg = t & 7;
      const float* src = xg + ((m0 + row) << 8) + cc * 64 + seg * 8;
      float4 f0 = *(const float4*)(src);
      float4 f1 = *(const float4*)(src + 4);
      uint4 w;
      w.x = pack2(f0.x, f0.y); w.y = pack2(f0.z, f0.w);
      w.z = pack2(f1.x, f1.y); w.w = pack2(f1.z, f1.w);
      *(uint4*)&sA[row * 72 + seg * 8] = w;
    }
    __syncthreads();
#pragma unroll
    for (int kk = 0; kk < 2; ++kk) {
      const int k0 = cc * 64 + kk * 32;
      bf16x8 a0 = *(const bf16x8*)&sA[(wave * 32 + r) * 72 + kk * 32 + q * 8];
      bf16x8 a1 = *(const bf16x8*)&sA[(wave * 32 + 16 + r) * 72 + kk * 32 + q * 8];
#pragma unroll
      for (int nt = 0; nt < 16; ++nt) {
        bf16x8 bw = *(const bf16x8*)&Wt[((nt * 16 + r) << 8) + k0 + q * 8];
        acc[0][nt] = __builtin_amdgcn_mfma_f32_16x16x32_bf16(a0, bw, acc[0][nt], 0, 0, 0);
        acc[1][nt] = __builtin_amdgcn_mfma_f32_16x16x32_bf16(a1, bw, acc[1][nt], 0, 0, 0);
      }
    }
  }
  // epilogue: bf16 store
#pragma unroll
  for (int mt = 0; mt < 2; ++mt)
#pragma unroll
    for (int nt = 0; nt < 16; ++nt)
#pragma unroll
      for (int g = 0; g < 4; ++g) {
        int row = m0 + wave * 32 + mt * 16 + q * 4 + g;
        out[(row << 8) + nt * 16 + r] = f2bf(acc[mt][nt][g]);
      }
}

// ---------------- halo_fast: per-window attention from precomputed XQ/XK/XV ----------------
struct alignas(16) SMF {
  unsigned short sK[224 * 40];   // K_h [kv][32]  rows 196..223 zero
  unsigned short sVt[32 * 232];  // V_h^T [32][kv] cols 196..231 zero
  unsigned short sQ[64 * 40];
  unsigned short sP[64 * 40];    // wave-private rows -> no barriers
  unsigned short sO[64 * 40];    // wave-private rows -> no barriers
};

__global__ __launch_bounds__(256, 3) void halo_fast_kernel(
    const unsigned short* __restrict__ XQ,
    const unsigned short* __restrict__ XK,
    const unsigned short* __restrict__ XV,
    const unsigned short* __restrict__ Wtp,   // Wproj^T bf16 [n][k]
    const float* __restrict__ PK,
    const float* __restrict__ PQ,
    const float* __restrict__ bp,
    float* __restrict__ out) {
  __shared__ SMF sm;
  const int wid = blockIdx.x;
  const int b = wid >> 8, widx = wid & 255;
  const int wy = widx >> 4, wx = widx & 15;
  const int tid = threadIdx.x;
  const int wave = tid >> 6, lane = tid & 63, q = lane >> 4, r = lane & 15;
  constexpr float SCALE = 0.17677669529663687f;

  // zero pad regions once (never overwritten)
  for (int idx = tid; idx < 1120; idx += 256) sm.sK[196 * 40 + idx] = 0;
  for (int idx = tid; idx < 1152; idx += 256) {
    int rr = idx / 36, c2 = idx - rr * 36;
    sm.sVt[rr * 232 + 196 + c2] = 0;
  }

  f32x4 oacc[16];
#pragma unroll
  for (int nt = 0; nt < 16; ++nt) oacc[nt] = (f32x4){0.f, 0.f, 0.f, 0.f};

  for (int h = 0; h < 8; ++h) {
    const int hc = h * 32;
    __syncthreads();  // previous head's reads done (also covers zero-init)
    // ---- stage K_h = XK + PK ----
    for (int t = tid; t < 784; t += 256) {
      int p = t >> 2, seg = t & 3;
      int i = div14(p), j = p - i * 14;
      int y = wy * 8 - 3 + i, x = wx * 8 - 3 + j;
      uint4 w = {0u, 0u, 0u, 0u};
      if ((unsigned)y < 128u && (unsigned)x < 128u) {
        int pix = (b * 128 + y) * 128 + x;
        bf16x8 kv = *(const bf16x8*)&XK[(pix << 8) + hc + seg * 8];
        const float* pk = PK + (p << 8) + hc + seg * 8;
        w.x = pack2(bf2f((unsigned short)kv[0]) + pk[0], bf2f((unsigned short)kv[1]) + pk[1]);
        w.y = pack2(bf2f((unsigned short)kv[2]) + pk[2], bf2f((unsigned short)kv[3]) + pk[3]);
        w.z = pack2(bf2f((unsigned short)kv[4]) + pk[4], bf2f((unsigned short)kv[5]) + pk[5]);
        w.w = pack2(bf2f((unsigned short)kv[6]) + pk[6], bf2f((unsigned short)kv[7]) + pk[7]);
      }
      *(uint4*)&sm.sK[p * 40 + seg * 8] = w;
    }
    // ---- stage V_h^T ----
    for (int t = tid; t < 784; t += 256) {
      int p = t >> 2, seg = t & 3;
      int i = div14(p), j = p - i * 14;
      int y = wy * 8 - 3 + i, x = wx * 8 - 3 + j;
      bf16x8 vv = {0, 0, 0, 0, 0, 0, 0, 0};
      if ((unsigned)y < 128u && (unsigned)x < 128u) {
        int pix = (b * 128 + y) * 128 + x;
        vv = *(const bf16x8*)&XV[(pix << 8) + hc + seg * 8];
      }
#pragma unroll
      for (int c = 0; c < 8; ++c) sm.sVt[(seg * 8 + c) * 232 + p] = (unsigned short)vv[c];
    }
    // ---- stage Q_h = XQ + PQ (256 tasks = 1/thread) ----
    {
      int m = tid >> 2, seg = tid & 3;
      int y = wy * 8 + (m >> 3), x = wx * 8 + (m & 7);
      int pix = (b * 128 + y) * 128 + x;
      bf16x8 qv = *(const bf16x8*)&XQ[(pix << 8) + hc + seg * 8];
      const float* pq = PQ + (m << 8) + hc + seg * 8;
      uint4 w;
      w.x = pack2(bf2f((unsigned short)qv[0]) + pq[0], bf2f((unsigned short)qv[1]) + pq[1]);
      w.y = pack2(bf2f((unsigned short)qv[2]) + pq[2], bf2f((unsigned short)qv[3]) + pq[3]);
      w.z = pack2(bf2f((unsigned short)qv[4]) + pq[4], bf2f((unsigned short)qv[5]) + pq[5]);
      w.w = pack2(bf2f((unsigned short)qv[6]) + pq[6], bf2f((unsigned short)qv[7]) + pq[7]);
      *(uint4*)&sm.sQ[m * 40 + seg * 8] = w;
    }
    __syncthreads();

    // ---- P2: S = Q K^T ----
    bf16x8 aq = *(const bf16x8*)&sm.sQ[(wave * 16 + r) * 40 + q * 8];
    f32x4 s[14];
#pragma unroll
    for (int nt = 0; nt < 14; ++nt) {
      bf16x8 bk = *(const bf16x8*)&sm.sK[(nt * 16 + r) * 40 + q * 8];
      f32x4 z = {0.f, 0.f, 0.f, 0.f};
      s[nt] = __builtin_amdgcn_mfma_f32_16x16x32_bf16(aq, bk, z, 0, 0, 0);
    }
#pragma unroll
    for (int nt = 0; nt < 14; ++nt) {
      int n = nt * 16 + r;
      int i = div14(n), j = n - i * 14;
      int y = wy * 8 - 3 + i, x = wx * 8 - 3 + j;
      bool valid = (n < 196) && ((unsigned)y < 128u) && ((unsigned)x < 128u);
#pragma unroll
      for (int g = 0; g < 4; ++g) s[nt][g] = valid ? s[nt][g] * SCALE : -1e30f;
    }
    float mx[4] = {-1e30f, -1e30f, -1e30f, -1e30f};
#pragma unroll
    for (int nt = 0; nt < 14; ++nt)
#pragma unroll
      for (int g = 0; g < 4; ++g) mx[g] = fmaxf(mx[g], s[nt][g]);
#pragma unroll
    for (int d = 1; d < 16; d <<= 1)
#pragma unroll
      for (int g = 0; g < 4; ++g) mx[g] = fmaxf(mx[g], __shfl_xor(mx[g], d));
    float sum[4] = {0.f, 0.f, 0.f, 0.f};
#pragma unroll
    for (int nt = 0; nt < 14; ++nt)
#pragma unroll
      for (int g = 0; g < 4; ++g) {
        float e = __expf(s[nt][g] - mx[g]);
        s[nt][g] = e; sum[g] += e;
      }
#pragma unroll
    for (int d = 1; d < 16; d <<= 1)
#pragma unroll
      for (int g = 0; g < 4; ++g) sum[g] += __shfl_xor(sum[g], d);
    float inv[4];
#pragma unroll
    for (int g = 0; g < 4; ++g) inv[g] = 1.f / sum[g];
#pragma unroll
    for (int nt = 0; nt < 14; ++nt)
#pragma unroll
      for (int g = 0; g < 4; ++g) s[nt][g] *= inv[g];

    // ---- P3: O = P @ V (sP rows are wave-private: no barriers) ----
    f32x4 ov[2];
    ov[0] = (f32x4){0.f, 0.f, 0.f, 0.f}; ov[1] = ov[0];
#pragma unroll
    for (int ck = 0; ck < 7; ++ck) {
#pragma unroll
      for (int tq = 0; tq < 2; ++tq)
#pragma unroll
        for (int g = 0; g < 4; ++g)
          sm.sP[(wave * 16 + q * 4 + g) * 40 + tq * 16 + r] = f2bf(s[ck * 2 + tq][g]);
      bf16x8 ap = *(const bf16x8*)&sm.sP[(wave * 16 + r) * 40 + q * 8];
#pragma unroll
      for (int t2 = 0; t2 < 2; ++t2) {
        bf16x8 bv = *(const bf16x8*)&sm.sVt[(t2 * 16 + r) * 232 + ck * 32 + q * 8];
        ov[t2] = __builtin_amdgcn_mfma_f32_16x16x32_bf16(ap, bv, ov[t2], 0, 0, 0);
      }
    }
#pragma unroll
    for (int t2 = 0; t2 < 2; ++t2)
#pragma unroll
      for (int g = 0; g < 4; ++g)
        sm.sO[(wave * 16 + q * 4 + g) * 40 + t2 * 16 + r] = f2bf(ov[t2][g]);

    // ---- P4: oacc += O_h @ Wproj[h*32:,:]  (sO wave-private) ----
    bf16x8 ao = *(const bf16x8*)&sm.sO[(wave * 16 + r) * 40 + q * 8];
#pragma unroll
    for (int nt = 0; nt < 16; ++nt) {
      bf16x8 bw = *(const bf16x8*)&Wtp[((nt * 16 + r) << 8) + hc + q * 8];
      oacc[nt] = __builtin_amdgcn_mfma_f32_16x16x32_bf16(ao, bw, oacc[nt], 0, 0, 0);
    }
  }

  // ---- epilogue ----
#pragma unroll
  for (int nt = 0; nt < 16; ++nt) {
    int col = nt * 16 + r;
    float bias = bp[col];
#pragma unroll
    for (int g = 0; g < 4; ++g) {
      int m = wave * 16 + q * 4 + g;
      int y = wy * 8 + (m >> 3), x = wx * 8 + (m & 7);
      out[(((b * 128 + y) * 128 + x) << 8) + col] = oacc[nt][g] + bias;
    }
  }
}

// ================= FALLBACK: round-2 fused kernel (known-good) =================
struct alignas(16) SM {
  unsigned short sX[208 * 40];
  unsigned short sK[224 * 40];
  unsigned short sVt[32 * 232];
  unsigned short sQ[64 * 40];
  unsigned short sP[64 * 40];
  unsigned short sO[64 * 40];
};

__global__ __launch_bounds__(256, 2) void halo_attn_kernel(
    const float* __restrict__ xg,
    const float* __restrict__ Wq, const float* __restrict__ Wk,
    const float* __restrict__ Wv, const float* __restrict__ Wp,
    const float* __restrict__ bp,
    const float* __restrict__ PK, const float* __restrict__ PQ,
    float* __restrict__ out) {
  __shared__ SM sm;
  const int wid = blockIdx.x;
  const int b = wid >> 8, widx = wid & 255;
  const int wy = widx >> 4, wx = widx & 15;
  const int tid = threadIdx.x;
  const int wave = tid >> 6, lane = tid & 63, q = lane >> 4, r = lane & 15;
  constexpr float SCALE = 0.17677669529663687f;

  for (int idx = tid; idx < 640; idx += 256) sm.sK[208 * 40 + idx] = 0;
  for (int idx = tid; idx < 1024; idx += 256) {
    int rr = idx >> 5, c2 = idx & 31;
    if (c2 < 24) sm.sVt[rr * 232 + 208 + c2] = 0;
  }
  f32x4 oacc[16];
#pragma unroll
  for (int nt = 0; nt < 16; ++nt) oacc[nt] = (f32x4){0.f, 0.f, 0.f, 0.f};
  const int ntA = wave & 1;
  const int qbase = (wave >> 1) * 2;
  const bool mainIsK = (wave < 2);
  const float* Wmain = mainIsK ? Wk : Wv;

  for (int h = 0; h < 8; ++h) {
    const int colMain = h * 32 + ntA * 16 + r;
    f32x4 acc[13];
#pragma unroll
    for (int mt = 0; mt < 13; ++mt) {
      if (mainIsK) {
#pragma unroll
        for (int g = 0; g < 4; ++g) acc[mt][g] = PK[(mt * 16 + q * 4 + g) * 256 + colMain];
      } else acc[mt] = (f32x4){0.f, 0.f, 0.f, 0.f};
    }
    f32x4 qacc[2];
#pragma unroll
    for (int tq = 0; tq < 2; ++tq)
#pragma unroll
      for (int g = 0; g < 4; ++g)
        qacc[tq][g] = PQ[((qbase + tq) * 16 + q * 4 + g) * 256 + colMain];
    bf16x8 bm = loadW8(Wmain + (q * 8) * 256 + colMain);
    bf16x8 bq = loadW8(Wq + (q * 8) * 256 + colMain);
    for (int cc = 0; cc < 8; ++cc) {
      __syncthreads();
      for (int tsk = tid; tsk < 832; tsk += 256) {
        int p = tsk >> 2, seg = tsk & 3;
        int i = div14(p), j = p - i * 14;
        int y = wy * 8 - 3 + i, x = wx * 8 - 3 + j;
        uint4 w = {0u, 0u, 0u, 0u};
        if (p < 196 && (unsigned)y < 128u && (unsigned)x < 128u) {
          const float* src = xg + (((b * 128 + y) * 128 + x) << 8) + cc * 32 + seg * 8;
          float4 f0 = *(const float4*)(src);
          float4 f1 = *(const float4*)(src + 4);
          w.x = pack2(f0.x, f0.y); w.y = pack2(f0.z, f0.w);
          w.z = pack2(f1.x, f1.y); w.w = pack2(f1.z, f1.w);
        }
        *(uint4*)&sm.sX[p * 40 + seg * 8] = w;
      }
      bf16x8 bmn = bm, bqn = bq;
      if (cc < 7) {
        bmn = loadW8(Wmain + ((cc + 1) * 32 + q * 8) * 256 + colMain);
        bqn = loadW8(Wq + ((cc + 1) * 32 + q * 8) * 256 + colMain);
      }
      __syncthreads();
#pragma unroll
      for (int mt = 0; mt < 13; ++mt) {
        bf16x8 a = *(const bf16x8*)&sm.sX[(mt * 16 + r) * 40 + q * 8];
        acc[mt] = __builtin_amdgcn_mfma_f32_16x16x32_bf16(a, bm, acc[mt], 0, 0, 0);
      }
#pragma unroll
      for (int tq = 0; tq < 2; ++tq) {
        int qm = (qbase + tq) * 16 + r;
        int p = ((qm >> 3) + 3) * 14 + (qm & 7) + 3;
        bf16x8 a = *(const bf16x8*)&sm.sX[p * 40 + q * 8];
        qacc[tq] = __builtin_amdgcn_mfma_f32_16x16x32_bf16(a, bq, qacc[tq], 0, 0, 0);
      }
      bm = bmn; bq = bqn;
    }
    if (mainIsK) {
#pragma unroll
      for (int mt = 0; mt < 13; ++mt)
#pragma unroll
        for (int g = 0; g < 4; ++g)
          sm.sK[(mt * 16 + q * 4 + g) * 40 + ntA * 16 + r] = f2bf(acc[mt][g]);
    } else {
#pragma unroll
      for (int mt = 0; mt < 13; ++mt) {
        short4 v4;
        v4.x = (short)f2bf(acc[mt][0]); v4.y = (short)f2bf(acc[mt][1]);
        v4.z = (short)f2bf(acc[mt][2]); v4.w = (short)f2bf(acc[mt][3]);
        *(short4*)&sm.sVt[(ntA * 16 + r) * 232 + mt * 16 + q * 4] = v4;
      }
    }
#pragma unroll
    for (int tq = 0; tq < 2; ++tq)
#pragma unroll
      for (int g = 0; g < 4; ++g)
        sm.sQ[((qbase + tq) * 16 + q * 4 + g) * 40 + ntA * 16 + r] = f2bf(qacc[tq][g]);
    __syncthreads();
    bf16x8 aq = *(const bf16x8*)&sm.sQ[(wave * 16 + r) * 40 + q * 8];
    f32x4 s[14];
#pragma unroll
    for (int nt = 0; nt < 14; ++nt) {
      bf16x8 bk = *(const bf16x8*)&sm.sK[(nt * 16 + r) * 40 + q * 8];
      f32x4 z = {0.f, 0.f, 0.f, 0.f};
      s[nt] = __builtin_amdgcn_mfma_f32_16x16x32_bf16(aq, bk, z, 0, 0, 0);
    }
#pragma unroll
    for (int nt = 0; nt < 14; ++nt) {
      int n = nt * 16 + r;
      int i = div14(n), j = n - i * 14;
      int y = wy * 8 - 3 + i, x = wx * 8 - 3 + j;
      bool valid = (n < 196) && ((unsigned)y < 128u) && ((unsigned)x < 128u);
#pragma unroll
      for (int g = 0; g < 4; ++g) s[nt][g] = valid ? s[nt][g] * SCALE : -1e30f;
    }
    float mx[4] = {-1e30f, -1e30f, -1e30f, -1e30f};
#pragma unroll
    for (int nt = 0; nt < 14; ++nt)
#pragma unroll
      for (int g = 0; g < 4; ++g) mx[g] = fmaxf(mx[g], s[nt][g]);
#pragma unroll
    for (int d = 1; d < 16; d <<= 1)
#pragma unroll
      for (int g = 0; g < 4; ++g) mx[g] = fmaxf(mx[g], __shfl_xor(mx[g], d));
    float sum[4] = {0.f, 0.f, 0.f, 0.f};
#pragma unroll
    for (int nt = 0; nt < 14; ++nt)
#pragma unroll
      for (int g = 0; g < 4; ++g) {
        float e = __expf(s[nt][g] - mx[g]);
        s[nt][g] = e; sum[g] += e;
      }
#pragma unroll
    for (int d = 1; d < 16; d <<= 1)
#pragma unroll
      for (int g = 0; g < 4; ++g) sum[g] += __shfl_xor(sum[g], d);
    float inv[4];
#pragma unroll
    for (int g = 0; g < 4; ++g) inv[g] = 1.f / sum[g];
#pragma unroll
    for (int nt = 0; nt < 14; ++nt)
#pragma unroll
      for (int g = 0; g < 4; ++g) s[nt][g] *= inv[g];
    f32x4 ov[2];
    ov[0] = (f32x4){0.f, 0.f, 0.f, 0.f}; ov[1] = ov[0];
#pragma unroll
    for (int ck = 0; ck < 7; ++ck) {
      __syncthreads();
#pragma unroll
      for (int tq = 0; tq < 2; ++tq)
#pragma unroll
        for (int g = 0; g < 4; ++g)
          sm.sP[(wave * 16 + q * 4 + g) * 40 + tq * 16 + r] = f2bf(s[ck * 2 + tq][g]);
      __syncthreads();
      bf16x8 ap = *(const bf16x8*)&sm.sP[(wave * 16 + r) * 40 + q * 8];
#pragma unroll
      for (int t2 = 0; t2 < 2; ++t2) {
        bf16x8 bv = *(const bf16x8*)&sm.sVt[(t2 * 16 + r) * 232 + ck * 32 + q * 8];
        ov[t2] = __builtin_amdgcn_mfma_f32_16x16x32_bf16(ap, bv, ov[t2], 0, 0, 0);
      }
    }
#pragma unroll
    for (int t2 = 0; t2 < 2; ++t2)
#pragma unroll
      for (int g = 0; g < 4; ++g)
        sm.sO[(wave * 16 + q * 4 + g) * 40 + t2 * 16 + r] = f2bf(ov[t2][g]);
    __syncthreads();
    bf16x8 ao = *(const bf16x8*)&sm.sO[(wave * 16 + r) * 40 + q * 8];
#pragma unroll
    for (int nt = 0; nt < 16; ++nt) {
      bf16x8 bw = loadW8(Wp + (h * 32 + q * 8) * 256 + nt * 16 + r);
      oacc[nt] = __builtin_amdgcn_mfma_f32_16x16x32_bf16(ao, bw, oacc[nt], 0, 0, 0);
    }
  }
#pragma unroll
  for (int nt = 0; nt < 16; ++nt) {
    int col = nt * 16 + r;
    float bias = bp[col];
#pragma unroll
    for (int g = 0; g < 4; ++g) {
      int m = wave * 16 + q * 4 + g;
      int y = wy * 8 + (m >> 3), x = wx * 8 + (m & 7);
      out[(((b * 128 + y) * 128 + x) << 8) + col] = oacc[nt][g] + bias;
    }
  }
}

extern "C" void kernel_launch(void* const* d_in, const int* in_sizes, int n_in,
                              void* d_out, int out_size, void* d_ws, size_t ws_size,
                              hipStream_t stream) {
  (void)in_sizes; (void)n_in; (void)out_size;
  const float* xg = (const float*)d_in[0];
  const float* Wq = (const float*)d_in[1];
  const float* Wk = (const float*)d_in[2];
  const float* Wv = (const float*)d_in[3];
  const float* Wp = (const float*)d_in[4];
  const float* bp = (const float*)d_in[5];
  float* out = (float*)d_out;

  // fast-path ws layout (bytes):
  //   XQ 0 .. 33554432, XK .. 67108864, XV .. 100663296,
  //   Wt4 .. 101187584, PK .. 101400576, PQ .. 101466112
  const size_t NEED = 101466112u;
  char* ws = (char*)d_ws;
  if (ws_size >= NEED) {
    unsigned short* XQ  = (unsigned short*)(ws);
    unsigned short* XK  = (unsigned short*)(ws + 33554432u);
    unsigned short* XV  = (unsigned short*)(ws + 67108864u);
    unsigned short* Wt4 = (unsigned short*)(ws + 100663296u);
    float* PK = (float*)(ws + 101187584u);
    float* PQ = (float*)(ws + 101400576u);
    pos_proj_kernel<<<dim3(272), dim3(256), 0, stream>>>(Wq, Wk, PK, PQ);
    wtrans_kernel<<<dim3(1024), dim3(256), 0, stream>>>(Wq, Wk, Wv, Wp, Wt4);
    qkv_gemm_kernel<<<dim3(512, 3), dim3(256), 0, stream>>>(xg, Wt4, XQ);
    halo_fast_kernel<<<dim3(1024), dim3(256), 0, stream>>>(
        XQ, XK, XV, Wt4 + 3 * 65536, PK, PQ, bp, out);
  } else {
    float* PK = (float*)ws;
    float* PQ = PK + 208 * 256;
    pos_proj_kernel<<<dim3(272), dim3(256), 0, stream>>>(Wq, Wk, PK, PQ);
    halo_attn_kernel<<<dim3(1024), dim3(256), 0, stream>>>(xg, Wq, Wk, Wv, Wp, bp, PK, PQ, out);
  }
}